// Round 22
// baseline (32.956 us; speedup 1.0000x reference)
//
#include <hip/hip_runtime.h>
#include <hip/hip_bf16.h>

typedef __attribute__((ext_vector_type(8))) short bf16x8;
typedef __attribute__((ext_vector_type(4))) float f32x4;

#define NBLK 512   // blocks; 512 threads (8 waves); 80 KiB LDS -> 2 blocks/CU, 4 waves/SIMD

__device__ __forceinline__ unsigned short f2bf(float f) {
    unsigned u = __float_as_uint(f);
    return (unsigned short)((u + 0x7fffu + ((u >> 16) & 1u)) >> 16);
}

__device__ __forceinline__ bf16x8 pack8(float4 x, float4 y) {
    bf16x8 r;
    r[0] = (short)f2bf(x.x); r[1] = (short)f2bf(x.y);
    r[2] = (short)f2bf(x.z); r[3] = (short)f2bf(x.w);
    r[4] = (short)f2bf(y.x); r[5] = (short)f2bf(y.y);
    r[6] = (short)f2bf(y.z); r[7] = (short)f2bf(y.w);
    return r;
}

__device__ __forceinline__ float ftanh(float x) {
    float e = __expf(2.f * x);
    return 1.f - 2.f / (e + 1.f);
}

// R16 structure (24.1us best) with ONE lever: occupancy 2 -> 4 waves/SIMD.
// LDS cut to 80 KiB (10 W matrices only; lin frags straight from global,
// L2-broadcast) -> 2 blocks/CU. 512 blocks x 8 waves = 4096 waves; wave-pairs
// redundantly ballot-sort a shared 64-edge window (no communication) and each
// computes a disjoint 2-tile half. No global_load_lds, no pre-pack dispatch,
// no load convoy (R19 suspects). Everything else byte-for-byte R16.
// Pre-committed: ~24us null / worse => plateau real, revert to R21 and declare.
// NOTE (R13/R14): block-level LDS binning regressed 10x — do not revisit.
// Layout (verified R1-R5): A row=lane&15, k=(lane>>4)*8+j; B col=lane&15
// (edge), same k; D col=lane&15 (edge), row=(lane>>4)*4+r -> f32x4 store/nt.
__global__ __launch_bounds__(512, 4) void k_fused(
    const int* __restrict__ ij, const float* __restrict__ desc,
    const float* __restrict__ layer1, const float* __restrict__ lin_w,
    const float* __restrict__ lin_b, float* __restrict__ out, int E) {

    __shared__ __align__(16) short wsm[10 * 512 * 8];   // 80 KiB; W matrices only

    for (int idx = threadIdx.x; idx < 10 * 512; idx += 512) {
        const int m = idx >> 9;
        const int fl = idx & 511;
        const int fi = fl >> 6, l = fl & 63;
        const int nt = fi >> 1, kk = fi & 1;
        const float* sp = layer1 + m * 4096 + (nt * 16 + (l & 15)) * 64 + kk * 32 + (l >> 4) * 8;
        float4 x = *(const float4*)sp;
        float4 y = *(const float4*)(sp + 4);
        *(bf16x8*)(&wsm[idx * 8]) = pack8(x, y);
    }

    const int lane = threadIdx.x & 63;
    const int col = lane & 15;
    const int g = lane >> 4;
    const int kb = g * 8;
    const bf16x8 zero8 = {0, 0, 0, 0, 0, 0, 0, 0};

    // lin fragments from global (L2-broadcast, once per wave)
    bf16x8 al[4][2];
    #pragma unroll
    for (int fi = 0; fi < 8; ++fi) {
        const int nt = fi >> 1, kk = fi & 1;
        const float* sp = lin_w + (nt * 16 + col) * 64 + kk * 32 + kb;
        al[nt][kk] = pack8(*(const float4*)sp, *(const float4*)(sp + 4));
    }

    __syncthreads();

    const int gwave = blockIdx.x * 8 + (threadIdx.x >> 6);   // 0..4095
    const int win = gwave >> 1;                               // shared window
    const int half = gwave & 1;                               // my 2-tile half
    const int base = win * 64;
    if (base >= E) return;

    // ---- in-wave sort of the window (redundant with partner wave; no comm) ----
    const int e_own = min(base + lane, E - 1);
    const int ty_own = ij[e_own];
    int rank = 0, below = 0;
    #pragma unroll
    for (int t = 0; t < 10; ++t) {
        const unsigned long long m = __ballot(ty_own == t);
        if (ty_own == t) rank = below + (int)__popcll(m & ((1ull << lane) - 1ull));
        below += (int)__popcll(m);
    }
    const int e_sorted = __builtin_amdgcn_ds_permute(rank << 2, e_own);
    const int ty_sorted = __builtin_amdgcn_ds_permute(rank << 2, ty_own);

    // ---- my 2 sorted 16-edge tiles ----
    #pragma unroll 1
    for (int q = 0; q < 2; ++q) {
        const int pbase = (half * 2 + q) * 16;
        const int e_t = __shfl(e_sorted, pbase + col);
        const int ty_t = __shfl(ty_sorted, pbase + col);
        const int ty_lo = __shfl(ty_sorted, pbase);
        const int ty_hi = __shfl(ty_sorted, pbase + 15);

        const float* dp = desc + (size_t)e_t * 64 + kb;
        const float4 x0 = *(const float4*)dp,        y0 = *(const float4*)(dp + 4);
        const float4 x1 = *(const float4*)(dp + 32), y1 = *(const float4*)(dp + 36);
        const bf16x8 b0 = pack8(x0, y0);
        const bf16x8 b1 = pack8(x1, y1);

        // lin path + zero W accumulators
        f32x4 zL[4], zW[4];
        #pragma unroll
        for (int nt = 0; nt < 4; ++nt) {
            f32x4 z = {0.f, 0.f, 0.f, 0.f};
            z = __builtin_amdgcn_mfma_f32_16x16x32_bf16(al[nt][0], b0, z, 0, 0, 0);
            zL[nt] = __builtin_amdgcn_mfma_f32_16x16x32_bf16(al[nt][1], b1, z, 0, 0, 0);
            zW[nt] = (f32x4){0.f, 0.f, 0.f, 0.f};
        }

        // W path over the tile's (sorted, contiguous) type range
        #pragma unroll 1
        for (int m = ty_lo; m <= ty_hi; ++m) {
            if (!__any(ty_t == m)) continue;
            const bf16x8 m0 = (ty_t == m) ? b0 : zero8;
            const bf16x8 m1 = (ty_t == m) ? b1 : zero8;
            #pragma unroll
            for (int nt = 0; nt < 4; ++nt) {
                const bf16x8 f0 = *(const bf16x8*)(&wsm[((m * 8 + nt * 2 + 0) * 64 + lane) * 8]);
                const bf16x8 f1 = *(const bf16x8*)(&wsm[((m * 8 + nt * 2 + 1) * 64 + lane) * 8]);
                zW[nt] = __builtin_amdgcn_mfma_f32_16x16x32_bf16(f0, m0, zW[nt], 0, 0, 0);
                zW[nt] = __builtin_amdgcn_mfma_f32_16x16x32_bf16(f1, m1, zW[nt], 0, 0, 0);
            }
        }

        float* op = out + (size_t)e_t * 64 + g * 4;
        #pragma unroll
        for (int nt = 0; nt < 4; ++nt) {
            const float4 bias = *(const float4*)(lin_b + nt * 16 + g * 4);
            f32x4 r;
            r[0] = ftanh(zW[nt][0]) + zL[nt][0] + bias.x;
            r[1] = ftanh(zW[nt][1]) + zL[nt][1] + bias.y;
            r[2] = ftanh(zW[nt][2]) + zL[nt][2] + bias.z;
            r[3] = ftanh(zW[nt][3]) + zL[nt][3] + bias.w;
            *(f32x4*)(op + nt * 16) = r;
        }
    }
}

extern "C" void kernel_launch(void* const* d_in, const int* in_sizes, int n_in,
                              void* d_out, int out_size, void* d_ws, size_t ws_size,
                              hipStream_t stream) {
    const int* ij = (const int*)d_in[0];
    const float* desc = (const float*)d_in[1];
    const float* layer1 = (const float*)d_in[2];
    const float* lin_w = (const float*)d_in[3];
    const float* lin_b = (const float*)d_in[4];
    float* out = (float*)d_out;
    const int E = in_sizes[0];

    k_fused<<<NBLK, 512, 0, stream>>>(ij, desc, layer1, lin_w, lin_b, out, E);
}

// Round 23
// 24.192 us; speedup vs baseline: 1.3622x; 1.3622x over previous
//
#include <hip/hip_runtime.h>
#include <hip/hip_bf16.h>

typedef __attribute__((ext_vector_type(8))) short bf16x8;
typedef __attribute__((ext_vector_type(4))) float f32x4;

#define NBLK 256   // blocks; 512 threads (8 waves); 1 block/CU (88 KB LDS), 2 waves/SIMD

__device__ __forceinline__ unsigned short f2bf(float f) {
    unsigned u = __float_as_uint(f);
    return (unsigned short)((u + 0x7fffu + ((u >> 16) & 1u)) >> 16);
}

__device__ __forceinline__ bf16x8 pack8(float4 x, float4 y) {
    bf16x8 r;
    r[0] = (short)f2bf(x.x); r[1] = (short)f2bf(x.y);
    r[2] = (short)f2bf(x.z); r[3] = (short)f2bf(x.w);
    r[4] = (short)f2bf(y.x); r[5] = (short)f2bf(y.y);
    r[6] = (short)f2bf(y.z); r[7] = (short)f2bf(y.w);
    return r;
}

__device__ __forceinline__ float ftanh(float x) {
    float e = __expf(2.f * x);
    return 1.f - 2.f / (e + 1.f);
}

// FINAL (reverted from R22's occupancy experiment, which regressed 24.3->33.0:
// 2 blocks/CU doubles per-block staging traffic + sort redundancy, and
// per-block fixed costs dominate this kernel). Measured-best configuration
// (R16/R21, 24.1-24.3us). Masked-fused single dispatch + in-wave ballot sort:
// each wave owns a 64-edge window, stable ballot-rank by type, ds_permute to
// sorted lane order -> 4 sorted 16-edge tiles; E[distinct types/tile] ~3.1
// (vs 8.1 unsorted). Weights staged once to LDS (88 KB); lin frags in regs.
// Complete lever ledger at this plateau: reschedule (R17 null), staging diet
// +1 dispatch (R20 -1.2), occupancy 4w/SIMD 1-block (R19 bundled, regress),
// occupancy 2-blocks/CU (R22 -8.7), LDS-traffic halving (R10 null), deep
// pipeline (R4 regress). R18 probe: steady ~13us with no pipe >41% busy;
// remaining ~10us over the 10.5us HBM floor = cold-fetch serialization (~5)
// + launch/ramp (~4-5) + sort/epilogue VALU (~1).
// NOTE (R13/R14): block-level LDS binning regressed 10x — do not revisit.
// Layout (verified R1-R5): A row=lane&15, k=(lane>>4)*8+j; B col=lane&15
// (edge), same k; D col=lane&15 (edge), row=(lane>>4)*4+r -> f32x4 store/nt.
__global__ __launch_bounds__(512, 2) void k_fused(
    const int* __restrict__ ij, const float* __restrict__ desc,
    const float* __restrict__ layer1, const float* __restrict__ lin_w,
    const float* __restrict__ lin_b, float* __restrict__ out, int E) {

    __shared__ __align__(16) short wsm[11 * 512 * 8];   // 88 KiB; m=10 is lin_w

    for (int idx = threadIdx.x; idx < 11 * 512; idx += 512) {
        const int m = idx >> 9;
        const int fl = idx & 511;
        const int fi = fl >> 6, l = fl & 63;
        const int nt = fi >> 1, kk = fi & 1;
        const float* src = (m < 10) ? (layer1 + m * 4096) : lin_w;
        const float* sp = src + (nt * 16 + (l & 15)) * 64 + kk * 32 + (l >> 4) * 8;
        float4 x = *(const float4*)sp;
        float4 y = *(const float4*)(sp + 4);
        *(bf16x8*)(&wsm[idx * 8]) = pack8(x, y);
    }

    const int lane = threadIdx.x & 63;
    const int col = lane & 15;
    const int g = lane >> 4;
    const int kb = g * 8;
    const bf16x8 zero8 = {0, 0, 0, 0, 0, 0, 0, 0};

    __syncthreads();

    // lin fragments resident in registers (m=10 staged frags)
    bf16x8 al[4][2];
    #pragma unroll
    for (int fi = 0; fi < 8; ++fi)
        al[fi >> 1][fi & 1] = *(const bf16x8*)(&wsm[((80 + fi) * 64 + lane) * 8]);

    const int gw = blockIdx.x * 8 + (threadIdx.x >> 6);
    const int base = gw * 64;
    if (base >= E) return;

    // ---- in-wave sort of the 64-edge window by type (stable ballot rank) ----
    const int e_own = min(base + lane, E - 1);
    const int ty_own = ij[e_own];
    int rank = 0, below = 0;
    #pragma unroll
    for (int t = 0; t < 10; ++t) {
        const unsigned long long m = __ballot(ty_own == t);
        if (ty_own == t) rank = below + (int)__popcll(m & ((1ull << lane) - 1ull));
        below += (int)__popcll(m);
    }
    const int e_sorted = __builtin_amdgcn_ds_permute(rank << 2, e_own);
    const int ty_sorted = __builtin_amdgcn_ds_permute(rank << 2, ty_own);

    // ---- 4 sorted 16-edge tiles ----
    #pragma unroll 1
    for (int tp = 0; tp < 4; ++tp) {
        const int pbase = tp * 16;
        const int e_t = __shfl(e_sorted, pbase + col);
        const int ty_t = __shfl(ty_sorted, pbase + col);
        const int ty_lo = __shfl(ty_sorted, pbase);
        const int ty_hi = __shfl(ty_sorted, pbase + 15);

        const float* dp = desc + (size_t)e_t * 64 + kb;
        const float4 x0 = *(const float4*)dp,        y0 = *(const float4*)(dp + 4);
        const float4 x1 = *(const float4*)(dp + 32), y1 = *(const float4*)(dp + 36);
        const bf16x8 b0 = pack8(x0, y0);
        const bf16x8 b1 = pack8(x1, y1);

        // lin path + zero W accumulators
        f32x4 zL[4], zW[4];
        #pragma unroll
        for (int nt = 0; nt < 4; ++nt) {
            f32x4 z = {0.f, 0.f, 0.f, 0.f};
            z = __builtin_amdgcn_mfma_f32_16x16x32_bf16(al[nt][0], b0, z, 0, 0, 0);
            zL[nt] = __builtin_amdgcn_mfma_f32_16x16x32_bf16(al[nt][1], b1, z, 0, 0, 0);
            zW[nt] = (f32x4){0.f, 0.f, 0.f, 0.f};
        }

        // W path over the tile's (sorted, contiguous) type range
        #pragma unroll 1
        for (int m = ty_lo; m <= ty_hi; ++m) {
            if (!__any(ty_t == m)) continue;
            const bf16x8 m0 = (ty_t == m) ? b0 : zero8;
            const bf16x8 m1 = (ty_t == m) ? b1 : zero8;
            #pragma unroll
            for (int nt = 0; nt < 4; ++nt) {
                const bf16x8 f0 = *(const bf16x8*)(&wsm[((m * 8 + nt * 2 + 0) * 64 + lane) * 8]);
                const bf16x8 f1 = *(const bf16x8*)(&wsm[((m * 8 + nt * 2 + 1) * 64 + lane) * 8]);
                zW[nt] = __builtin_amdgcn_mfma_f32_16x16x32_bf16(f0, m0, zW[nt], 0, 0, 0);
                zW[nt] = __builtin_amdgcn_mfma_f32_16x16x32_bf16(f1, m1, zW[nt], 0, 0, 0);
            }
        }

        float* op = out + (size_t)e_t * 64 + g * 4;
        #pragma unroll
        for (int nt = 0; nt < 4; ++nt) {
            const float4 bias = *(const float4*)(lin_b + nt * 16 + g * 4);
            f32x4 r;
            r[0] = ftanh(zW[nt][0]) + zL[nt][0] + bias.x;
            r[1] = ftanh(zW[nt][1]) + zL[nt][1] + bias.y;
            r[2] = ftanh(zW[nt][2]) + zL[nt][2] + bias.z;
            r[3] = ftanh(zW[nt][3]) + zL[nt][3] + bias.w;
            *(f32x4*)(op + nt * 16) = r;
        }
    }
}

extern "C" void kernel_launch(void* const* d_in, const int* in_sizes, int n_in,
                              void* d_out, int out_size, void* d_ws, size_t ws_size,
                              hipStream_t stream) {
    const int* ij = (const int*)d_in[0];
    const float* desc = (const float*)d_in[1];
    const float* layer1 = (const float*)d_in[2];
    const float* lin_w = (const float*)d_in[3];
    const float* lin_b = (const float*)d_in[4];
    float* out = (float*)d_out;
    const int E = in_sizes[0];

    k_fused<<<NBLK, 512, 0, stream>>>(ij, desc, layer1, lin_w, lin_b, out, E);
}